// Round 5
// baseline (4277.450 us; speedup 1.0000x reference)
//
#include <hip/hip_runtime.h>
#include <math.h>
#include <limits.h>

#define T_STEPS 32
#define BATCH   16
#define KBEAM   4
#define BKR     64      // BATCH*KBEAM rows
#define HD      512
#define VOC     32000
#define G3      1536    // 3*HD
#define SOS_TOK 1
#define EOS_TOK 2
#define NSP     (VOC/64)      // 500 N-blocks of logits GEMM
#define NE      (NSP*4)       // 2000 top-4 partial entries per row
#define NBG     (G3/64)       // 24 N-blocks of gates GEMM
#define FMBL    2             // m-blocks per final block

// ---- workspace layout (float offsets) ----
#define OFF_HCUR   ((size_t)0)
#define OFF_GBUF   (OFF_HCUR + (size_t)BKR*HD)
#define OFF_HNEW   (OFF_GBUF + (size_t)2*BKR*G3)
#define OFF_LSE    (OFF_HNEW + (size_t)T_STEPS*BKR*HD)
#define OFF_SS     (OFF_LSE + (size_t)T_STEPS*BKR)
#define OFF_SCORES (OFF_SS + BKR)
#define OFF_HNFIN  (OFF_SCORES + (size_t)T_STEPS*BKR)
#define OFF_PV     (OFF_HNFIN + (size_t)BKR*HD)            // [64][NE]
#define OFF_PM     (OFF_PV + (size_t)BKR*NE)               // [64][NSP]
#define OFF_PS     (OFF_PM + (size_t)BKR*NSP)
#define OFF_FEND   (OFF_PS + (size_t)BKR*NSP)
// ---- int region (int offsets), base = (int*)(w + OFF_FEND) ----
#define IOFF_INP    0
#define IOFF_PREDS  64
#define IOFF_SYMS   (IOFF_PREDS + T_STEPS*BKR)
#define IOFF_RMAP   (IOFF_SYMS + T_STEPS*BKR)
#define IOFF_PC     (IOFF_RMAP + T_STEPS*BATCH)
#define IOFF_GCNT   (IOFF_PC + BKR*NE)
#define IOFF_LCNT   (IOFF_GCNT + T_STEPS)
#define IOFF_END    (IOFF_LCNT + T_STEPS)
// ---- short region (short offsets), base = (unsigned short*)(wi + IOFF_END) ----
#define S_WOH   ((size_t)0)                        // [NSP][16][2048]
#define S_WOL   (S_WOH + (size_t)NSP*16*2048)      // 16384000
#define S_WGH   (S_WOL + (size_t)NSP*16*2048)      // [2][NBG][16][2048]
#define S_WGL   (S_WGH + (size_t)2*NBG*16*2048)
#define S_HNH   (S_WGL + (size_t)2*NBG*16*2048)    // [T][64][512]
#define S_HNL   (S_HNH + (size_t)T_STEPS*BKR*HD)
#define S_HCH   (S_HNL + (size_t)T_STEPS*BKR*HD)   // [64][512]
#define S_HCL   (S_HCH + (size_t)BKR*HD)
#define S_EIH   (S_HCL + (size_t)BKR*HD)
#define S_EIL   (S_EIH + (size_t)BKR*HD)
#define S_END   (S_EIL + (size_t)BKR*HD)

// ---- output layout (float offsets into d_out) ----
#define O_HID  ((size_t)T_STEPS*BATCH*VOC)
#define O_SSRT (O_HID + (size_t)BATCH*HD)
#define O_LENS (O_SSRT + BATCH*KBEAM)
#define O_SEQS (O_LENS + BATCH*KBEAM)

typedef short bf16x8 __attribute__((ext_vector_type(8)));
typedef float f32x4  __attribute__((ext_vector_type(4)));

__device__ __forceinline__ unsigned short f2bf(float x){
    unsigned u = __float_as_uint(x);
    return (unsigned short)((u + 0x7fffu + ((u >> 16) & 1u)) >> 16);
}
__device__ __forceinline__ float bf2f(unsigned short h){
    return __uint_as_float(((unsigned)h) << 16);
}

__device__ __forceinline__ void dump_C(f32x4 (&acc)[4], float (*Cs)[65], int wave, int lane){
    #pragma unroll
    for (int g = 0; g < 4; ++g){
        int row = g * 16 + (lane >> 4) * 4;
        int col = wave * 16 + (lane & 15);
        #pragma unroll
        for (int r = 0; r < 4; ++r) Cs[row + r][col] = acc[g][r];
    }
}

// ============ top-4 insertion with JAX tie semantics (val desc, cand asc) ============
__device__ __forceinline__ void ins4(float* bv, int* bc, float s, int c){
    bool g0 = (s > bv[0]) || (s == bv[0] && c < bc[0]);
    bool g1 = (s > bv[1]) || (s == bv[1] && c < bc[1]);
    bool g2 = (s > bv[2]) || (s == bv[2] && c < bc[2]);
    bool g3 = (s > bv[3]) || (s == bv[3] && c < bc[3]);
    if (g0){ bv[3]=bv[2];bc[3]=bc[2]; bv[2]=bv[1];bc[2]=bc[1]; bv[1]=bv[0];bc[1]=bc[0]; bv[0]=s; bc[0]=c; }
    else if (g1){ bv[3]=bv[2];bc[3]=bc[2]; bv[2]=bv[1];bc[2]=bc[1]; bv[1]=s; bc[1]=c; }
    else if (g2){ bv[3]=bv[2];bc[3]=bc[2]; bv[2]=s; bc[2]=c; }
    else if (g3){ bv[3]=s; bc[3]=c; }
}

// =================================================================================
// ============================ PREPACKED (fast) path ==============================
// =================================================================================

// W (fp32, HD x N row-major) -> tiles [N/64][16][64n x 32k] hi/lo bf16.
// Packed tile element [r][c] = W[(kt*32+c)*N + bx*64 + r]; a thread's MFMA B-frag
// is the 16B run at (wave*16+fr)*32 + fq*8 — directly loadable, no LDS needed.
__global__ __launch_bounds__(256) void prepack_kernel(const float* __restrict__ W, int N,
    unsigned short* __restrict__ oh, unsigned short* __restrict__ ol)
{
    const int bx = blockIdx.x, kt = blockIdx.y, tid = threadIdx.x;
    const int bn = tid >> 2, kq = (tid & 3) * 8;
    union { unsigned short u[8]; uint4 v; } h8, l8;
    #pragma unroll
    for (int j = 0; j < 8; ++j){
        float x = W[(size_t)(kt*32 + kq + j) * (size_t)N + bx*64 + bn];
        unsigned short h = f2bf(x);
        h8.u[j] = h; l8.u[j] = f2bf(x - bf2f(h));
    }
    const size_t base = ((size_t)bx*16 + kt) * 2048 + (size_t)tid * 8;
    *(uint4*)(oh + base) = h8.v;
    *(uint4*)(ol + base) = l8.v;
}

// ---------------------------------------------------------------------------------
// gates GEMM (LDS-free, zero-barrier K-loop, fragments direct from L2/L3)
// + fused GRU combine (finisher blocks, bounds-guarded window).
// MFMA sequence identical to verified kernel => bitwise-identical results.
// ---------------------------------------------------------------------------------
__global__ __launch_bounds__(256) void gates_pre_kernel(
    const unsigned short* __restrict__ eih, const unsigned short* __restrict__ eil,
    const unsigned short* __restrict__ hch, const unsigned short* __restrict__ hcl,
    const unsigned short* __restrict__ wgh, const unsigned short* __restrict__ wgl,
    const float* __restrict__ b_ih, const float* __restrict__ b_hh,
    float* __restrict__ gbuf,
    const float* __restrict__ h_cur, float* __restrict__ h_new,
    unsigned short* __restrict__ hnh, unsigned short* __restrict__ hnl,
    int* __restrict__ gcnt)
{
    __shared__ int comm[1];
    const int z = blockIdx.y, bx = blockIdx.x, n0 = bx * 64;
    const int tid = threadIdx.x;
    const unsigned short* ahg = z ? hch : eih;
    const unsigned short* alg = z ? hcl : eil;
    const size_t bt = ((size_t)z*NBG + bx) * 16 * 2048;
    const int wave = tid >> 6, lane = tid & 63;
    const int fr = lane & 15, fq = lane >> 4;
    const unsigned short* bh_p = wgh + bt + (wave*16 + fr)*32 + fq*8;
    const unsigned short* bl_p = wgl + bt + (wave*16 + fr)*32 + fq*8;
    const unsigned short* ah_p = ahg + (size_t)fr*512 + fq*8;
    const unsigned short* al_p = alg + (size_t)fr*512 + fq*8;
    f32x4 acc[4];
    #pragma unroll
    for (int g = 0; g < 4; ++g) acc[g] = (f32x4){0.f,0.f,0.f,0.f};
    #pragma unroll 4
    for (int kt = 0; kt < 16; ++kt){
        bf16x8 bh = *(const bf16x8*)(bh_p + kt*2048);
        bf16x8 bl = *(const bf16x8*)(bl_p + kt*2048);
        #pragma unroll
        for (int g = 0; g < 4; ++g){
            bf16x8 ah = *(const bf16x8*)(ah_p + g*16*512 + kt*32);
            bf16x8 al = *(const bf16x8*)(al_p + g*16*512 + kt*32);
            acc[g] = __builtin_amdgcn_mfma_f32_16x16x32_bf16(ah, bh, acc[g], 0, 0, 0);
            acc[g] = __builtin_amdgcn_mfma_f32_16x16x32_bf16(ah, bl, acc[g], 0, 0, 0);
            acc[g] = __builtin_amdgcn_mfma_f32_16x16x32_bf16(al, bh, acc[g], 0, 0, 0);
        }
    }
    // direct fragment->global epilogue
    const float* bias = z ? b_hh : b_ih;
    const int col = wave*16 + fr;
    const float bz = bias[n0 + col];
    float* gp = gbuf + (size_t)z * BKR * G3 + n0 + col;
    #pragma unroll
    for (int g = 0; g < 4; ++g){
        const int r0 = g*16 + fq*4;
        #pragma unroll
        for (int r = 0; r < 4; ++r)
            gp[(size_t)(r0 + r) * G3] = acc[g][r] + bz;
    }
    // ---- finisher: last 8 blocks apply GRU combine (64-col slice each) ----
    __syncthreads();
    if (tid == 0){
        __threadfence();
        comm[0] = atomicAdd(gcnt, 1);
    }
    __syncthreads();
    const int old = comm[0];
    if (old >= 2*NBG - 8 && old < 2*NBG){
        if (tid == 0){
            while (__hip_atomic_load(gcnt, __ATOMIC_ACQUIRE, __HIP_MEMORY_SCOPE_AGENT) < 2*NBG)
                __builtin_amdgcn_s_sleep(1);
        }
        __syncthreads();
        __threadfence();
        const int slice = old - (2*NBG - 8);
        for (int x = tid; x < 64*64; x += 256){
            const int rr = x >> 6, j = (slice << 6) + (x & 63);
            const int xi = rr * HD + j;
            const float* gi = gbuf + (size_t)rr * G3;
            const float* gh = gbuf + (size_t)BKR * G3 + (size_t)rr * G3;
            float ir = gi[j], iz = gi[j + 512], inn = gi[j + 1024];
            float hr = gh[j], hz = gh[j + 512], hnv = gh[j + 1024];
            float r  = 1.f / (1.f + expf(-(ir + hr)));
            float zz = 1.f / (1.f + expf(-(iz + hz)));
            float n  = tanhf(inn + r * hnv);
            float v = (1.f - zz) * n + zz * h_cur[xi];
            h_new[xi] = v;
            unsigned short h = f2bf(v);
            hnh[xi] = h; hnl[xi] = f2bf(v - bf2f(h));
        }
    }
}

// ---------------------------------------------------------------------------------
// logits GEMM (LDS-free, zero-barrier K-loop) + per-block top4/LSE partials
// ---------------------------------------------------------------------------------
__global__ __launch_bounds__(256) void logits_pre_kernel(
    const unsigned short* __restrict__ hnh, const unsigned short* __restrict__ hnl,
    const unsigned short* __restrict__ woh, const unsigned short* __restrict__ wol,
    const float* __restrict__ bo,
    float* __restrict__ pv, int* __restrict__ pc, float* __restrict__ pm, float* __restrict__ ps)
{
    __shared__ float Cs[64][65];
    const int bx = blockIdx.x, n0 = bx * 64;
    const int tid = threadIdx.x;
    const int wave = tid >> 6, lane = tid & 63;
    const int fr = lane & 15, fq = lane >> 4;
    const unsigned short* bh_p = woh + (size_t)bx*16*2048 + (wave*16 + fr)*32 + fq*8;
    const unsigned short* bl_p = wol + (size_t)bx*16*2048 + (wave*16 + fr)*32 + fq*8;
    const unsigned short* ah_p = hnh + (size_t)fr*512 + fq*8;
    const unsigned short* al_p = hnl + (size_t)fr*512 + fq*8;
    f32x4 acc[4];
    #pragma unroll
    for (int g = 0; g < 4; ++g) acc[g] = (f32x4){0.f,0.f,0.f,0.f};
    #pragma unroll 4
    for (int kt = 0; kt < 16; ++kt){
        bf16x8 bh = *(const bf16x8*)(bh_p + kt*2048);
        bf16x8 bl = *(const bf16x8*)(bl_p + kt*2048);
        #pragma unroll
        for (int g = 0; g < 4; ++g){
            bf16x8 ah = *(const bf16x8*)(ah_p + g*16*512 + kt*32);
            bf16x8 al = *(const bf16x8*)(al_p + g*16*512 + kt*32);
            acc[g] = __builtin_amdgcn_mfma_f32_16x16x32_bf16(ah, bh, acc[g], 0, 0, 0);
            acc[g] = __builtin_amdgcn_mfma_f32_16x16x32_bf16(ah, bl, acc[g], 0, 0, 0);
            acc[g] = __builtin_amdgcn_mfma_f32_16x16x32_bf16(al, bh, acc[g], 0, 0, 0);
        }
    }
    dump_C(acc, Cs, wave, lane);
    __syncthreads();
    const int row = tid >> 2, c0 = (tid & 3) * 16;
    float bv[4] = {-INFINITY,-INFINITY,-INFINITY,-INFINITY};
    int bc[4] = {INT_MAX, INT_MAX, INT_MAX, INT_MAX};
    float m = -INFINITY, s = 0.f;
    #pragma unroll
    for (int j = 0; j < 16; ++j){
        float x = Cs[row][c0 + j] + bo[n0 + c0 + j];
        if (x > m){ s = s * expf(m - x) + 1.f; m = x; }
        else s += expf(x - m);
        ins4(bv, bc, x, n0 + c0 + j);
    }
    #pragma unroll
    for (int o = 1; o < 4; o <<= 1){
        float ov[4]; int oc[4];
        #pragma unroll
        for (int q = 0; q < 4; ++q){ ov[q] = __shfl_xor(bv[q], o); oc[q] = __shfl_xor(bc[q], o); }
        #pragma unroll
        for (int q = 0; q < 4; ++q) ins4(bv, bc, ov[q], oc[q]);
        float m2 = __shfl_xor(m, o), s2 = __shfl_xor(s, o);
        float M = fmaxf(m, m2);
        s = s * expf(m - M) + s2 * expf(m2 - M);
        m = M;
    }
    if ((tid & 3) == 0){
        const size_t base = (size_t)row * NE + (size_t)bx * 4;
        #pragma unroll
        for (int q = 0; q < 4; ++q){ pv[base + q] = bv[q]; pc[base + q] = bc[q]; }
        pm[row * NSP + bx] = m; ps[row * NSP + bx] = s;
    }
}

// final GEMM (LDS-free): grid (m-quads, NSP) so same-Wo-tile blocks are adjacent.
__global__ __launch_bounds__(256) void final_pre_kernel(
    const unsigned short* __restrict__ hnh, const unsigned short* __restrict__ hnl,
    const int* __restrict__ rmap, const float* __restrict__ lse_all,
    const unsigned short* __restrict__ woh, const unsigned short* __restrict__ wol,
    const float* __restrict__ bo, float* __restrict__ out)
{
    __shared__ int sidx[64*FMBL]; __shared__ float subm[64*FMBL];
    const int tid = threadIdx.x;
    const int bx = blockIdx.y, n0 = bx * 64;
    const int mbase = blockIdx.x * (64 * FMBL);
    if (tid < 64*FMBL){ int g = rmap[mbase + tid]; sidx[tid] = g; subm[tid] = lse_all[g]; }
    __syncthreads();
    const int wave = tid >> 6, lane = tid & 63;
    const int fr = lane & 15, fq = lane >> 4;
    int rows[FMBL*4];
    #pragma unroll
    for (int mb = 0; mb < FMBL; ++mb)
        #pragma unroll
        for (int g = 0; g < 4; ++g) rows[mb*4 + g] = sidx[mb*64 + g*16 + fr];
    const unsigned short* bh_p = woh + (size_t)bx*16*2048 + (wave*16 + fr)*32 + fq*8;
    const unsigned short* bl_p = wol + (size_t)bx*16*2048 + (wave*16 + fr)*32 + fq*8;
    f32x4 acc[FMBL][4];
    #pragma unroll
    for (int mb = 0; mb < FMBL; ++mb)
        #pragma unroll
        for (int g = 0; g < 4; ++g) acc[mb][g] = (f32x4){0.f,0.f,0.f,0.f};
    #pragma unroll 2
    for (int kt = 0; kt < 16; ++kt){
        bf16x8 bh = *(const bf16x8*)(bh_p + kt*2048);
        bf16x8 bl = *(const bf16x8*)(bl_p + kt*2048);
        #pragma unroll
        for (int mb = 0; mb < FMBL; ++mb){
            #pragma unroll
            for (int g = 0; g < 4; ++g){
                const size_t ao = (size_t)rows[mb*4 + g] * 512 + kt*32 + fq*8;
                bf16x8 ah = *(const bf16x8*)(hnh + ao);
                bf16x8 al = *(const bf16x8*)(hnl + ao);
                acc[mb][g] = __builtin_amdgcn_mfma_f32_16x16x32_bf16(ah, bh, acc[mb][g], 0, 0, 0);
                acc[mb][g] = __builtin_amdgcn_mfma_f32_16x16x32_bf16(ah, bl, acc[mb][g], 0, 0, 0);
                acc[mb][g] = __builtin_amdgcn_mfma_f32_16x16x32_bf16(al, bh, acc[mb][g], 0, 0, 0);
            }
        }
    }
    // direct fragment->global epilogue
    const int col = n0 + wave*16 + fr;
    const float bz = bo[col];
    #pragma unroll
    for (int mb = 0; mb < FMBL; ++mb){
        #pragma unroll
        for (int g = 0; g < 4; ++g){
            const int rb = mb*64 + g*16 + fq*4;
            #pragma unroll
            for (int r = 0; r < 4; ++r){
                const int rowi = rb + r;
                out[(size_t)(mbase + rowi) * VOC + col] = acc[mb][g][r] + bz - subm[rowi];
            }
        }
    }
}

// =================================================================================
// ======================== fallback (R4, fp32-convert) path =======================
// =================================================================================
__device__ __forceinline__ void mfma_core(
    const float* __restrict__ Abase, const int* __restrict__ ridx, int mbase,
    const float* __restrict__ B, int ldb, int n0,
    unsigned short (&Ah)[64][40], unsigned short (&Al)[64][40],
    unsigned short (&Bh)[64][40], unsigned short (&Bl)[64][40],
    int (&sidx)[64], f32x4 (&acc)[4])
{
    const int tid = threadIdx.x;
    if (tid < 64) sidx[tid] = ridx ? ridx[mbase + tid] : (mbase + tid);
    #pragma unroll
    for (int g = 0; g < 4; ++g) acc[g] = (f32x4){0.f, 0.f, 0.f, 0.f};
    const int wave = tid >> 6, lane = tid & 63;
    const int am = tid >> 2, ak0 = (tid & 3) * 8;
    const int bn = tid & 63, br0 = (tid >> 6) * 8;
    __syncthreads();
    const float* bcol = B + n0 + bn;
    for (int kt = 0; kt < 16; ++kt){
        {
            const float* ap = Abase + (size_t)sidx[am] * HD + kt * 32 + ak0;
            float4 x0 = *(const float4*)ap, x1 = *(const float4*)(ap + 4);
            float xs[8] = {x0.x, x0.y, x0.z, x0.w, x1.x, x1.y, x1.z, x1.w};
            union { unsigned short u[8]; uint4 v; } h8, l8;
            #pragma unroll
            for (int j = 0; j < 8; ++j){
                unsigned short h = f2bf(xs[j]);
                h8.u[j] = h; l8.u[j] = f2bf(xs[j] - bf2f(h));
            }
            *(uint4*)&Ah[am][ak0] = h8.v;
            *(uint4*)&Al[am][ak0] = l8.v;
        }
        {
            const float* bp = bcol + (size_t)(kt * 32 + br0) * ldb;
            union { unsigned short u[8]; uint4 v; } h8, l8;
            #pragma unroll
            for (int j = 0; j < 8; ++j){
                float x = bp[(size_t)j * ldb];
                unsigned short h = f2bf(x);
                h8.u[j] = h; l8.u[j] = f2bf(x - bf2f(h));
            }
            *(uint4*)&Bh[bn][br0] = h8.v;
            *(uint4*)&Bl[bn][br0] = l8.v;
        }
        __syncthreads();
        bf16x8 bh = *(const bf16x8*)&Bh[wave * 16 + (lane & 15)][(lane >> 4) * 8];
        bf16x8 bl = *(const bf16x8*)&Bl[wave * 16 + (lane & 15)][(lane >> 4) * 8];
        #pragma unroll
        for (int g = 0; g < 4; ++g){
            bf16x8 ah = *(const bf16x8*)&Ah[g * 16 + (lane & 15)][(lane >> 4) * 8];
            bf16x8 al = *(const bf16x8*)&Al[g * 16 + (lane & 15)][(lane >> 4) * 8];
            acc[g] = __builtin_amdgcn_mfma_f32_16x16x32_bf16(ah, bh, acc[g], 0, 0, 0);
            acc[g] = __builtin_amdgcn_mfma_f32_16x16x32_bf16(ah, bl, acc[g], 0, 0, 0);
            acc[g] = __builtin_amdgcn_mfma_f32_16x16x32_bf16(al, bh, acc[g], 0, 0, 0);
        }
        __syncthreads();
    }
}

__global__ __launch_bounds__(256) void gates_mfma_kernel(
    const float* __restrict__ E, const int* __restrict__ inp, const float* __restrict__ h_cur,
    const float* __restrict__ W_ih, const float* __restrict__ W_hh,
    const float* __restrict__ b_ih, const float* __restrict__ b_hh,
    float* __restrict__ gbuf)
{
    __shared__ unsigned short Ah[64][40], Al[64][40], Bh[64][40], Bl[64][40];
    __shared__ int sidx[64];
    __shared__ float Cs[64][65];
    const int z = blockIdx.y;
    const int n0 = blockIdx.x * 64;
    const int tid = threadIdx.x;
    f32x4 acc[4];
    mfma_core(z ? h_cur : E, z ? nullptr : inp, 0,
              z ? W_hh : W_ih, G3, n0, Ah, Al, Bh, Bl, sidx, acc);
    dump_C(acc, Cs, tid >> 6, tid & 63);
    __syncthreads();
    const float* bias = z ? b_hh : b_ih;
    const int row = tid >> 2, c0 = (tid & 3) * 16;
    float* gp = gbuf + (size_t)z * BKR * G3 + (size_t)row * G3 + n0 + c0;
    #pragma unroll
    for (int q = 0; q < 4; ++q){
        float4 bz = *(const float4*)(bias + n0 + c0 + q * 4);
        float4 v;
        v.x = Cs[row][c0 + q*4 + 0] + bz.x;
        v.y = Cs[row][c0 + q*4 + 1] + bz.y;
        v.z = Cs[row][c0 + q*4 + 2] + bz.z;
        v.w = Cs[row][c0 + q*4 + 3] + bz.w;
        *(float4*)(gp + q * 4) = v;
    }
}

__global__ __launch_bounds__(256) void logits_topk_kernel(const float* __restrict__ h_new,
    const float* __restrict__ Wo, const float* __restrict__ bo,
    float* __restrict__ pv, int* __restrict__ pc, float* __restrict__ pm, float* __restrict__ ps)
{
    __shared__ unsigned short Ah[64][40], Al[64][40], Bh[64][40], Bl[64][40];
    __shared__ int sidx[64];
    __shared__ float Cs[64][65];
    const int bx = blockIdx.x, n0 = bx * 64;
    const int tid = threadIdx.x;
    f32x4 acc[4];
    mfma_core(h_new, nullptr, 0, Wo, VOC, n0, Ah, Al, Bh, Bl, sidx, acc);
    dump_C(acc, Cs, tid >> 6, tid & 63);
    __syncthreads();
    const int row = tid >> 2, c0 = (tid & 3) * 16;
    float bv[4] = {-INFINITY,-INFINITY,-INFINITY,-INFINITY};
    int bc[4] = {INT_MAX, INT_MAX, INT_MAX, INT_MAX};
    float m = -INFINITY, s = 0.f;
    #pragma unroll
    for (int j = 0; j < 16; ++j){
        float x = Cs[row][c0 + j] + bo[n0 + c0 + j];
        if (x > m){ s = s * expf(m - x) + 1.f; m = x; }
        else s += expf(x - m);
        ins4(bv, bc, x, n0 + c0 + j);
    }
    #pragma unroll
    for (int o = 1; o < 4; o <<= 1){
        float ov[4]; int oc[4];
        #pragma unroll
        for (int q = 0; q < 4; ++q){ ov[q] = __shfl_xor(bv[q], o); oc[q] = __shfl_xor(bc[q], o); }
        #pragma unroll
        for (int q = 0; q < 4; ++q) ins4(bv, bc, ov[q], oc[q]);
        float m2 = __shfl_xor(m, o), s2 = __shfl_xor(s, o);
        float M = fmaxf(m, m2);
        s = s * expf(m - M) + s2 * expf(m2 - M);
        m = M;
    }
    if ((tid & 3) == 0){
        const size_t base = (size_t)row * NE + (size_t)bx * 4;
        #pragma unroll
        for (int q = 0; q < 4; ++q){ pv[base + q] = bv[q]; pc[base + q] = bc[q]; }
        pm[row * NSP + bx] = m; ps[row * NSP + bx] = s;
    }
}

__global__ __launch_bounds__(256) void final_mfma_kernel(const float* __restrict__ h_new_all,
    const int* __restrict__ rmap, const float* __restrict__ lse_all,
    const float* __restrict__ Wo, const float* __restrict__ bo, float* __restrict__ out)
{
    __shared__ unsigned short Ah[64][40], Al[64][40], Bh[64][40], Bl[64][40];
    __shared__ int sidx[64];
    __shared__ float Cs[64][65];
    __shared__ float subm[64];
    const int n0 = blockIdx.x * 64, mb = blockIdx.y * 64;
    const int tid = threadIdx.x;
    f32x4 acc[4];
    mfma_core(h_new_all, rmap, mb, Wo, VOC, n0, Ah, Al, Bh, Bl, sidx, acc);
    dump_C(acc, Cs, tid >> 6, tid & 63);
    if (tid < 64) subm[tid] = lse_all[sidx[tid]];
    __syncthreads();
    const int row = tid >> 2, c0 = (tid & 3) * 16;
    const float sub = subm[row];
    float* op = out + (size_t)(mb + row) * VOC + n0 + c0;
    #pragma unroll
    for (int q = 0; q < 4; ++q){
        float4 bz = *(const float4*)(bo + n0 + c0 + q * 4);
        float4 v;
        v.x = Cs[row][c0 + q*4 + 0] + bz.x - sub;
        v.y = Cs[row][c0 + q*4 + 1] + bz.y - sub;
        v.z = Cs[row][c0 + q*4 + 2] + bz.z - sub;
        v.w = Cs[row][c0 + q*4 + 3] + bz.w - sub;
        *(float4*)(op + q * 4) = v;
    }
}

// =================================================================================
// ============================ shared non-GEMM kernels ============================
// =================================================================================

__global__ void gru_combine_kernel(const float* __restrict__ gbuf, const float* __restrict__ h_cur,
    float* __restrict__ h_new, unsigned short* __restrict__ hnh, unsigned short* __restrict__ hnl)
{
    int x = blockIdx.x * 256 + threadIdx.x;
    int i = x >> 9, j = x & 511;
    const float* gi = gbuf + (size_t)i * G3;
    const float* gh = gbuf + (size_t)BKR * G3 + (size_t)i * G3;
    float ir = gi[j], iz = gi[j + 512], inn = gi[j + 1024];
    float hr = gh[j], hz = gh[j + 512], hnv = gh[j + 1024];
    float r  = 1.f / (1.f + expf(-(ir + hr)));
    float zz = 1.f / (1.f + expf(-(iz + hz)));
    float n  = tanhf(inn + r * hnv);
    float v = (1.f - zz) * n + zz * h_cur[x];
    h_new[x] = v;
    if (hnh){
        unsigned short h = f2bf(v);
        hnh[x] = h; hnl[x] = f2bf(v - bf2f(h));
    }
}

__global__ __launch_bounds__(256) void topk_phase_b(
    const float* __restrict__ pv, const int* __restrict__ pc,
    const float* __restrict__ pm, const float* __restrict__ ps,
    int t,
    float* __restrict__ scores_all, int* __restrict__ preds_all, int* __restrict__ syms_all,
    float* __restrict__ ss, int* __restrict__ inp, float* __restrict__ lse_all,
    const float* __restrict__ h_new, float* __restrict__ h_cur,
    const float* __restrict__ E,
    unsigned short* __restrict__ hch, unsigned short* __restrict__ hcl,
    unsigned short* __restrict__ eih, unsigned short* __restrict__ eil)
{
    const int b = blockIdx.x, tid = threadIdx.x;
    const int wave = tid >> 6, lane = tid & 63;
    const int row = b * KBEAM + wave;

    float bv[4] = {-INFINITY,-INFINITY,-INFINITY,-INFINITY};
    int bc[4] = {INT_MAX, INT_MAX, INT_MAX, INT_MAX};
    for (int e = lane; e < NE; e += 64)
        ins4(bv, bc, pv[(size_t)row * NE + e], pc[(size_t)row * NE + e]);
    #pragma unroll
    for (int o = 1; o < 64; o <<= 1){
        float ov[4]; int oc[4];
        #pragma unroll
        for (int q = 0; q < 4; ++q){ ov[q] = __shfl_xor(bv[q], o); oc[q] = __shfl_xor(bc[q], o); }
        #pragma unroll
        for (int q = 0; q < 4; ++q) ins4(bv, bc, ov[q], oc[q]);
    }
    float m = -INFINITY, s = 0.f;
    for (int e = lane; e < NSP; e += 64){
        float m2 = pm[row * NSP + e], s2 = ps[row * NSP + e];
        float M = fmaxf(m, m2);
        s = s * expf(m - M) + s2 * expf(m2 - M);
        m = M;
    }
    #pragma unroll
    for (int o = 1; o < 64; o <<= 1){
        float m2 = __shfl_xor(m, o), s2 = __shfl_xor(s, o);
        float M = fmaxf(m, m2);
        s = s * expf(m - M) + s2 * expf(m2 - M);
        m = M;
    }
    __shared__ float rtv[KBEAM][4]; __shared__ int rtc[KBEAM][4];
    __shared__ float rlse[KBEAM];
    if (lane == 0){
        #pragma unroll
        for (int q = 0; q < 4; ++q){ rtv[wave][q] = bv[q]; rtc[wave][q] = bc[q]; }
        rlse[wave] = m + logf(s);
    }
    __syncthreads();
    __shared__ int spred[KBEAM]; __shared__ int ssym[KBEAM];
    if (tid == 0){
        float gv[4] = {-INFINITY,-INFINITY,-INFINITY,-INFINITY};
        int gc[4] = {INT_MAX, INT_MAX, INT_MAX, INT_MAX};
        #pragma unroll
        for (int kl = 0; kl < KBEAM; ++kl){
            const int r2 = b * KBEAM + kl;
            float lse = rlse[kl];
            lse_all[t * BKR + r2] = lse;
            float off = ss[r2] - lse;
            if (off == -INFINITY){
                #pragma unroll
                for (int q = 0; q < 4; ++q) ins4(gv, gc, -INFINITY, kl * VOC + q);
            } else {
                #pragma unroll
                for (int q = 0; q < 4; ++q) ins4(gv, gc, rtv[kl][q] + off, kl * VOC + rtc[kl][q]);
            }
        }
        #pragma unroll
        for (int u = 0; u < KBEAM; ++u){
            int cand = gc[u]; float val = gv[u];
            int sym = cand % VOC; int pg = b * KBEAM + cand / VOC;
            int slot = b * KBEAM + u;
            scores_all[t * BKR + slot] = val;
            syms_all[t * BKR + slot] = sym;
            preds_all[t * BKR + slot] = pg;
            ss[slot] = (sym == EOS_TOK) ? -INFINITY : val;
            inp[slot] = sym;
            spred[u] = pg; ssym[u] = sym;
        }
    }
    __syncthreads();
    for (int x = tid; x < KBEAM * HD; x += 256){
        int u = x >> 9, j = x & 511;
        const int idx = (b * KBEAM + u) * HD + j;
        float v = h_new[spred[u] * HD + j];
        h_cur[idx] = v;
        if (hch){
            unsigned short h = f2bf(v);
            hch[idx] = h; hcl[idx] = f2bf(v - bf2f(h));
            float e = E[(size_t)ssym[u] * HD + j];
            unsigned short eh = f2bf(e);
            eih[idx] = eh; eil[idx] = f2bf(e - bf2f(eh));
        }
    }
}

__global__ void init_kernel(const float* __restrict__ enc_h, const float* __restrict__ E,
    float* __restrict__ h_cur, float* __restrict__ ss, int* __restrict__ inp,
    unsigned short* __restrict__ hch, unsigned short* __restrict__ hcl,
    unsigned short* __restrict__ eih, unsigned short* __restrict__ eil,
    int* __restrict__ cnts)
{
    const int i = blockIdx.x;
    for (int j = threadIdx.x; j < HD; j += blockDim.x){
        float v = enc_h[(i & (BATCH - 1)) * HD + j];
        h_cur[i * HD + j] = v;
        if (hch){
            const int idx = i * HD + j;
            unsigned short h = f2bf(v);
            hch[idx] = h; hcl[idx] = f2bf(v - bf2f(h));
            float e = E[(size_t)SOS_TOK * HD + j];
            unsigned short eh = f2bf(e);
            eih[idx] = eh; eil[idx] = f2bf(e - bf2f(eh));
        }
    }
    if (i == 0 && threadIdx.x < BKR){
        ss[threadIdx.x] = ((threadIdx.x & (KBEAM - 1)) == 0) ? 0.f : -INFINITY;
        inp[threadIdx.x] = SOS_TOK;
    }
    if (i == 1 && cnts){
        for (int x = threadIdx.x; x < 2*T_STEPS; x += blockDim.x) cnts[x] = 0;
    }
}

// ================= backtrack (single block, LDS-staged, parallel) =================
__global__ __launch_bounds__(256) void backtrack_kernel(
    const float* __restrict__ scores_all, const int* __restrict__ preds_all, const int* __restrict__ syms_all,
    const float* __restrict__ h_new_all, float* __restrict__ hn_fin,
    int* __restrict__ rmap, float* __restrict__ out)
{
    __shared__ int   l_syms[T_STEPS*BKR];
    __shared__ int   l_preds[T_STEPS*BKR];
    __shared__ float l_scores[T_STEPS*BKR];
    __shared__ int   outrow_s[T_STEPS*BKR];
    __shared__ int   cursym_s[T_STEPS*BKR];
    __shared__ int tpred[64]; __shared__ float sfin[64]; __shared__ int lensq[64];
    __shared__ int eosf[BATCH];
    __shared__ int orow[64], csym[64], npred_s[64];
    __shared__ int cp_slot[64], cp_src[64]; __shared__ int nc_b[BATCH];
    __shared__ int reidx[64];
    const int tid = threadIdx.x;

    for (int x = tid; x < T_STEPS*BKR; x += 256){
        l_syms[x]   = syms_all[x];
        l_preds[x]  = preds_all[x];
        l_scores[x] = scores_all[x];
    }
    for (int x = tid; x < BKR*HD; x += 256) hn_fin[x] = 0.f;
    __syncthreads();

    if (tid < BATCH){
        const int b = tid;
        float v[KBEAM]; int used[KBEAM];
        #pragma unroll
        for (int k = 0; k < KBEAM; ++k){ v[k] = l_scores[(T_STEPS-1)*BKR + b*KBEAM + k]; used[k] = 0; }
        #pragma unroll
        for (int u = 0; u < KBEAM; ++u){
            int best = -1; float bvv = 0.f;
            #pragma unroll
            for (int k = 0; k < KBEAM; ++k) if (!used[k] && (best < 0 || v[k] > bvv)){ best = k; bvv = v[k]; }
            used[best] = 1;
            tpred[b*KBEAM+u] = b*KBEAM + best;
            sfin[b*KBEAM+u] = bvv;
            lensq[b*KBEAM+u] = T_STEPS;
        }
        eosf[b] = 0;
    }
    __syncthreads();

    for (int t = T_STEPS-1; t >= 0; --t){
        if (tid < 64){
            int tp = tpred[tid];
            orow[tid]    = tp;
            csym[tid]    = l_syms[t*BKR + tp];
            npred_s[tid] = l_preds[t*BKR + tp];
        }
        __syncthreads();
        if (tid < BATCH){
            const int b = tid;
            int eos[KBEAM]; int cnt = 0;
            #pragma unroll
            for (int k = 0; k < KBEAM; ++k) eos[k] = (l_syms[t*BKR + b*KBEAM + k] == EOS_TOK);
            int nc = 0;
            #pragma unroll
            for (int k = 0; k < KBEAM; ++k) if (eos[k]){
                int higher = 0;
                #pragma unroll
                for (int k2 = k+1; k2 < KBEAM; ++k2) higher += eos[k2];
                int occ = eosf[b] + higher;
                int rk = KBEAM - (occ % KBEAM) - 1;
                int slot = b*KBEAM + rk;
                int j = b*KBEAM + k;
                npred_s[slot] = l_preds[t*BKR + j];
                orow[slot]    = j;
                csym[slot]    = l_syms[t*BKR + j];
                sfin[slot]    = l_scores[t*BKR + j];
                lensq[slot]   = t + 1;
                cp_slot[b*KBEAM + nc] = slot;
                cp_src[b*KBEAM + nc]  = l_preds[t*BKR + j];
                ++nc; ++cnt;
            }
            nc_b[b] = nc;
            eosf[b] += cnt;
        }
        __syncthreads();
        if (tid < 64){
            outrow_s[t*BKR + tid] = orow[tid];
            cursym_s[t*BKR + tid] = csym[tid];
            tpred[tid] = npred_s[tid];
        }
        {
            const int e = tid >> 2;
            const int eb = e >> 2, eq = e & 3;
            if (eq < nc_b[eb]){
                const int slot = cp_slot[eb*KBEAM + eq];
                const int src  = cp_src[eb*KBEAM + eq];
                const float4* sp = (const float4*)(h_new_all + (size_t)(t*BKR + src)*HD);
                float4* dp = (float4*)(hn_fin + (size_t)slot*HD);
                for (int j = (tid & 3); j < HD/4; j += 4) dp[j] = sp[j];
            }
        }
        __syncthreads();
    }

    if (tid < BATCH){
        const int b = tid;
        float v[KBEAM]; int used[KBEAM];
        #pragma unroll
        for (int k = 0; k < KBEAM; ++k){ v[k] = sfin[b*KBEAM+k]; used[k] = 0; }
        #pragma unroll
        for (int u = 0; u < KBEAM; ++u){
            int best = -1; float bvv = 0.f;
            #pragma unroll
            for (int k = 0; k < KBEAM; ++k) if (!used[k] && (best < 0 || v[k] > bvv)){ best = k; bvv = v[k]; }
            used[best] = 1;
            reidx[b*KBEAM+u] = best;
            out[O_SSRT + b*KBEAM + u] = bvv;
            out[O_LENS + b*KBEAM + u] = (float)lensq[b*KBEAM + best];
        }
    }
    __syncthreads();
    for (int x = tid; x < T_STEPS*BATCH; x += 256){
        int t2 = x >> 4, b = x & 15;
        rmap[x] = t2*BKR + outrow_s[t2*BKR + b*KBEAM + reidx[b*KBEAM]];
    }
    for (int x = tid; x < T_STEPS*BKR; x += 256){
        int t2 = x >> 6, rem = x & 63, b = rem >> 2, k = rem & 3;
        out[O_SEQS + x] = (float)cursym_s[t2*BKR + b*KBEAM + reidx[b*KBEAM + k]];
    }
    for (int x = tid; x < BATCH*HD; x += 256){
        int b = x >> 9, j = x & 511;
        out[O_HID + x] = hn_fin[(b*KBEAM + reidx[b*KBEAM])*HD + j];
    }
}

extern "C" void kernel_launch(void* const* d_in, const int* in_sizes, int n_in,
                              void* d_out, int out_size, void* d_ws, size_t ws_size,
                              hipStream_t stream)
{
    const float* enc_h = (const float*)d_in[0];
    const float* E     = (const float*)d_in[1];
    const float* W_ih  = (const float*)d_in[2];
    const float* W_hh  = (const float*)d_in[3];
    const float* b_ih  = (const float*)d_in[4];
    const float* b_hh  = (const float*)d_in[5];
    const float* Wo    = (const float*)d_in[6];
    const float* bo    = (const float*)d_in[7];
    float* out = (float*)d_out;

    float* w = (float*)d_ws;
    float* h_cur      = w + OFF_HCUR;
    float* gbuf       = w + OFF_GBUF;
    float* h_new_all  = w + OFF_HNEW;
    float* lse_all    = w + OFF_LSE;
    float* ss         = w + OFF_SS;
    float* scores_all = w + OFF_SCORES;
    float* hn_fin     = w + OFF_HNFIN;
    float* pv         = w + OFF_PV;
    float* pm         = w + OFF_PM;
    float* ps         = w + OFF_PS;
    int* wi         = (int*)(w + OFF_FEND);
    int* inp        = wi + IOFF_INP;
    int* preds_all  = wi + IOFF_PREDS;
    int* syms_all   = wi + IOFF_SYMS;
    int* rmap       = wi + IOFF_RMAP;
    int* pc         = wi + IOFF_PC;
    int* gcnt       = wi + IOFF_GCNT;
    unsigned short* sb = (unsigned short*)(wi + IOFF_END);
    unsigned short* woh = sb + S_WOH;
    unsigned short* wol = sb + S_WOL;
    unsigned short* wgh = sb + S_WGH;
    unsigned short* wgl = sb + S_WGL;
    unsigned short* hnh = sb + S_HNH;
    unsigned short* hnl = sb + S_HNL;
    unsigned short* hch = sb + S_HCH;
    unsigned short* hcl = sb + S_HCL;
    unsigned short* eih = sb + S_EIH;
    unsigned short* eil = sb + S_EIL;

    const size_t NEED = (size_t)OFF_FEND*4 + (size_t)IOFF_END*4 + (size_t)S_END*2;
    const bool pre = (ws_size >= NEED);

    init_kernel<<<dim3(BKR), 256, 0, stream>>>(enc_h, E, h_cur, ss, inp,
        pre ? hch : nullptr, hcl, eih, eil, pre ? gcnt : nullptr);
    if (pre){
        prepack_kernel<<<dim3(NSP, 16), 256, 0, stream>>>(Wo, VOC, woh, wol);
        prepack_kernel<<<dim3(NBG, 16), 256, 0, stream>>>(W_ih, G3, wgh, wgl);
        prepack_kernel<<<dim3(NBG, 16), 256, 0, stream>>>(W_hh, G3,
            wgh + (size_t)NBG*16*2048, wgl + (size_t)NBG*16*2048);
    }
    for (int t = 0; t < T_STEPS; ++t){
        float* h_new_t = h_new_all + (size_t)t * BKR * HD;
        unsigned short* hnh_t = hnh + (size_t)t * BKR * HD;
        unsigned short* hnl_t = hnl + (size_t)t * BKR * HD;
        if (pre){
            gates_pre_kernel<<<dim3(NBG, 2), 256, 0, stream>>>(eih, eil, hch, hcl,
                wgh, wgl, b_ih, b_hh, gbuf, h_cur, h_new_t, hnh_t, hnl_t, gcnt + t);
            logits_pre_kernel<<<dim3(NSP), 256, 0, stream>>>(hnh_t, hnl_t, woh, wol, bo,
                pv, pc, pm, ps);
            topk_phase_b<<<dim3(BATCH), 256, 0, stream>>>(pv, pc, pm, ps, t, scores_all, preds_all, syms_all,
                ss, inp, lse_all, h_new_t, h_cur, E,
                hch, hcl, eih, eil);
        } else {
            gates_mfma_kernel<<<dim3(NBG, 2), 256, 0, stream>>>(E, inp, h_cur, W_ih, W_hh, b_ih, b_hh, gbuf);
            gru_combine_kernel<<<dim3(BKR*HD/256), 256, 0, stream>>>(gbuf, h_cur, h_new_t,
                nullptr, hnl_t);
            logits_topk_kernel<<<dim3(NSP), 256, 0, stream>>>(h_new_t, Wo, bo, pv, pc, pm, ps);
            topk_phase_b<<<dim3(BATCH), 256, 0, stream>>>(pv, pc, pm, ps, t, scores_all, preds_all, syms_all,
                ss, inp, lse_all, h_new_t, h_cur, E,
                nullptr, hcl, eih, eil);
        }
    }
    backtrack_kernel<<<dim3(1), 256, 0, stream>>>(scores_all, preds_all, syms_all, h_new_all, hn_fin,
                                                  rmap, out);
    if (pre){
        final_pre_kernel<<<dim3((T_STEPS*BATCH)/(64*FMBL), NSP), 256, 0, stream>>>(
            hnh, hnl, rmap, lse_all, woh, wol, bo, out);
    } else {
        final_mfma_kernel<<<dim3(NSP, T_STEPS*BATCH/64), 256, 0, stream>>>(h_new_all, rmap, lse_all, Wo, bo, out);
    }
}

// Round 6
// 2565.964 us; speedup vs baseline: 1.6670x; 1.6670x over previous
//
#include <hip/hip_runtime.h>
#include <math.h>
#include <limits.h>

#define T_STEPS 32
#define BATCH   16
#define KBEAM   4
#define BKR     64      // BATCH*KBEAM rows
#define HD      512
#define VOC     32000
#define G3      1536    // 3*HD
#define SOS_TOK 1
#define EOS_TOK 2
#define NSP     (VOC/64)      // 500 N-blocks of logits GEMM
#define NE      (NSP*4)       // 2000 top-4 partial entries per row
#define NBG     (G3/64)       // 24 N-blocks of gates GEMM
#define FMBL    2             // m-blocks per final block

// ---- workspace layout (float offsets) ----
#define OFF_HCUR   ((size_t)0)
#define OFF_GBUF   (OFF_HCUR + (size_t)BKR*HD)
#define OFF_HNEW   (OFF_GBUF + (size_t)2*BKR*G3)
#define OFF_LSE    (OFF_HNEW + (size_t)T_STEPS*BKR*HD)
#define OFF_SS     (OFF_LSE + (size_t)T_STEPS*BKR)
#define OFF_SCORES (OFF_SS + BKR)
#define OFF_HNFIN  (OFF_SCORES + (size_t)T_STEPS*BKR)
#define OFF_PV     (OFF_HNFIN + (size_t)BKR*HD)            // [64][NE]
#define OFF_PM     (OFF_PV + (size_t)BKR*NE)               // [64][NSP]
#define OFF_PS     (OFF_PM + (size_t)BKR*NSP)
#define OFF_FEND   (OFF_PS + (size_t)BKR*NSP)
// ---- int region (int offsets), base = (int*)(w + OFF_FEND) ----
#define IOFF_INP    0
#define IOFF_PREDS  64
#define IOFF_SYMS   (IOFF_PREDS + T_STEPS*BKR)
#define IOFF_RMAP   (IOFF_SYMS + T_STEPS*BKR)
#define IOFF_PC     (IOFF_RMAP + T_STEPS*BATCH)
#define IOFF_GCNT   (IOFF_PC + BKR*NE)
#define IOFF_LCNT   (IOFF_GCNT + T_STEPS)
#define IOFF_END    (IOFF_LCNT + T_STEPS)
// ---- short region (short offsets), base = (unsigned short*)(wi + IOFF_END) ----
#define S_WOH   ((size_t)0)                        // [NSP][16][2048]
#define S_WOL   (S_WOH + (size_t)NSP*16*2048)      // 16384000
#define S_WGH   (S_WOL + (size_t)NSP*16*2048)      // [2][NBG][16][2048]
#define S_WGL   (S_WGH + (size_t)2*NBG*16*2048)
#define S_HNH   (S_WGL + (size_t)2*NBG*16*2048)    // [T][64][512]
#define S_HNL   (S_HNH + (size_t)T_STEPS*BKR*HD)
#define S_HCH   (S_HNL + (size_t)T_STEPS*BKR*HD)   // [64][512]
#define S_HCL   (S_HCH + (size_t)BKR*HD)
#define S_EIH   (S_HCL + (size_t)BKR*HD)
#define S_EIL   (S_EIH + (size_t)BKR*HD)
#define S_END   (S_EIL + (size_t)BKR*HD)

// ---- output layout (float offsets into d_out) ----
#define O_HID  ((size_t)T_STEPS*BATCH*VOC)
#define O_SSRT (O_HID + (size_t)BATCH*HD)
#define O_LENS (O_SSRT + BATCH*KBEAM)
#define O_SEQS (O_LENS + BATCH*KBEAM)

typedef short bf16x8 __attribute__((ext_vector_type(8)));
typedef float f32x4  __attribute__((ext_vector_type(4)));

// Unpadded LDS tile: [64 rows][32 shorts] = 4096 B = exactly 256 threads x 16 B.
// Fragment ds_read at (r*32 + fq*8) shorts is 2-way bank-aliased only (free).
#define TS2 2048

__device__ __forceinline__ unsigned short f2bf(float x){
    unsigned u = __float_as_uint(x);
    return (unsigned short)((u + 0x7fffu + ((u >> 16) & 1u)) >> 16);
}
__device__ __forceinline__ float bf2f(unsigned short h){
    return __uint_as_float(((unsigned)h) << 16);
}

// async global->LDS, 16 B per lane; LDS dest is linear (base + lane*16)
__device__ __forceinline__ void gl2lds16(const unsigned short* g, unsigned short* l){
    __builtin_amdgcn_global_load_lds(
        (const __attribute__((address_space(1))) unsigned int*)((const void*)g),
        (__attribute__((address_space(3))) unsigned int*)((void*)l),
        16, 0, 0);
}

__device__ __forceinline__ void dump_C(f32x4 (&acc)[4], float (*Cs)[65], int wave, int lane){
    #pragma unroll
    for (int g = 0; g < 4; ++g){
        int row = g * 16 + (lane >> 4) * 4;
        int col = wave * 16 + (lane & 15);
        #pragma unroll
        for (int r = 0; r < 4; ++r) Cs[row + r][col] = acc[g][r];
    }
}

// ============ top-4 insertion with JAX tie semantics (val desc, cand asc) ============
__device__ __forceinline__ void ins4(float* bv, int* bc, float s, int c){
    bool g0 = (s > bv[0]) || (s == bv[0] && c < bc[0]);
    bool g1 = (s > bv[1]) || (s == bv[1] && c < bc[1]);
    bool g2 = (s > bv[2]) || (s == bv[2] && c < bc[2]);
    bool g3 = (s > bv[3]) || (s == bv[3] && c < bc[3]);
    if (g0){ bv[3]=bv[2];bc[3]=bc[2]; bv[2]=bv[1];bc[2]=bc[1]; bv[1]=bv[0];bc[1]=bc[0]; bv[0]=s; bc[0]=c; }
    else if (g1){ bv[3]=bv[2];bc[3]=bc[2]; bv[2]=bv[1];bc[2]=bc[1]; bv[1]=s; bc[1]=c; }
    else if (g2){ bv[3]=bv[2];bc[3]=bc[2]; bv[2]=s; bc[2]=c; }
    else if (g3){ bv[3]=s; bc[3]=c; }
}

// =================================================================================
// ============================ PREPACKED (fast) path ==============================
// =================================================================================

// W (fp32, HD x N row-major) -> tiles [N/64][16][64n x 32k] hi/lo bf16
__global__ __launch_bounds__(256) void prepack_kernel(const float* __restrict__ W, int N,
    unsigned short* __restrict__ oh, unsigned short* __restrict__ ol)
{
    const int bx = blockIdx.x, kt = blockIdx.y, tid = threadIdx.x;
    const int bn = tid >> 2, kq = (tid & 3) * 8;
    union { unsigned short u[8]; uint4 v; } h8, l8;
    #pragma unroll
    for (int j = 0; j < 8; ++j){
        float x = W[(size_t)(kt*32 + kq + j) * (size_t)N + bx*64 + bn];
        unsigned short h = f2bf(x);
        h8.u[j] = h; l8.u[j] = f2bf(x - bf2f(h));
    }
    const size_t base = ((size_t)bx*16 + kt) * 2048 + (size_t)tid * 8;
    *(uint4*)(oh + base) = h8.v;
    *(uint4*)(ol + base) = l8.v;
}

// ---------------------------------------------------------------------------------
// gates GEMM: dbuf LDS, staged via global_load_lds (width 16), 1 barrier/kt.
// MFMA sequence identical to verified kernel => bitwise-identical results.
// ---------------------------------------------------------------------------------
__global__ __launch_bounds__(256) void gates_pre_kernel(
    const unsigned short* __restrict__ eih, const unsigned short* __restrict__ eil,
    const unsigned short* __restrict__ hch, const unsigned short* __restrict__ hcl,
    const unsigned short* __restrict__ wgh, const unsigned short* __restrict__ wgl,
    const float* __restrict__ b_ih, const float* __restrict__ b_hh,
    float* __restrict__ gbuf)
{
    __shared__ __align__(16) unsigned short sm[2*4*TS2];   // 32768 B
    const int z = blockIdx.y, bx = blockIdx.x, n0 = bx * 64;
    const int tid = threadIdx.x;
    const unsigned short* ahg = z ? hch : eih;
    const unsigned short* alg = z ? hcl : eil;
    const size_t bt = ((size_t)z*NBG + bx) * 16 * 2048;
    const unsigned short* bth = wgh + bt;
    const unsigned short* btl = wgl + bt;
    const int row = tid >> 2, kq = (tid & 3) * 8;
    const int wave = tid >> 6, lane = tid & 63;
    const int fr = lane & 15, fq = lane >> 4;
    const unsigned short* a_h_src = ahg + (size_t)row*512 + kq;
    const unsigned short* a_l_src = alg + (size_t)row*512 + kq;
    const unsigned short* b_h_src = bth + (size_t)tid*8;
    const unsigned short* b_l_src = btl + (size_t)tid*8;
    f32x4 acc[4];
    #pragma unroll
    for (int g = 0; g < 4; ++g) acc[g] = (f32x4){0.f,0.f,0.f,0.f};
    {
        unsigned short* nb = sm;
        gl2lds16(a_h_src,      nb + 0*TS2 + tid*8);
        gl2lds16(a_l_src,      nb + 1*TS2 + tid*8);
        gl2lds16(b_h_src,      nb + 2*TS2 + tid*8);
        gl2lds16(b_l_src,      nb + 3*TS2 + tid*8);
    }
    __syncthreads();
    for (int kt = 0; kt < 16; ++kt){
        if (kt < 15){
            unsigned short* nb = sm + (((kt+1)&1)*4)*TS2;
            gl2lds16(a_h_src + (kt+1)*32,   nb + 0*TS2 + tid*8);
            gl2lds16(a_l_src + (kt+1)*32,   nb + 1*TS2 + tid*8);
            gl2lds16(b_h_src + (kt+1)*2048, nb + 2*TS2 + tid*8);
            gl2lds16(b_l_src + (kt+1)*2048, nb + 3*TS2 + tid*8);
        }
        const unsigned short* cb = sm + ((kt&1)*4)*TS2;
        bf16x8 bh = *(const bf16x8*)(cb + 2*TS2 + (wave*16 + fr)*32 + fq*8);
        bf16x8 bl = *(const bf16x8*)(cb + 3*TS2 + (wave*16 + fr)*32 + fq*8);
        #pragma unroll
        for (int g = 0; g < 4; ++g){
            bf16x8 ah = *(const bf16x8*)(cb + 0*TS2 + (g*16 + fr)*32 + fq*8);
            bf16x8 al = *(const bf16x8*)(cb + 1*TS2 + (g*16 + fr)*32 + fq*8);
            acc[g] = __builtin_amdgcn_mfma_f32_16x16x32_bf16(ah, bh, acc[g], 0, 0, 0);
            acc[g] = __builtin_amdgcn_mfma_f32_16x16x32_bf16(ah, bl, acc[g], 0, 0, 0);
            acc[g] = __builtin_amdgcn_mfma_f32_16x16x32_bf16(al, bh, acc[g], 0, 0, 0);
        }
        __syncthreads();
    }
    // direct fragment->global epilogue (no Cs round-trip)
    const float* bias = z ? b_hh : b_ih;
    const int col = wave*16 + fr;
    const float bz = bias[n0 + col];
    float* gp = gbuf + (size_t)z * BKR * G3 + n0 + col;
    #pragma unroll
    for (int g = 0; g < 4; ++g){
        const int r0 = g*16 + fq*4;
        #pragma unroll
        for (int r = 0; r < 4; ++r)
            gp[(size_t)(r0 + r) * G3] = acc[g][r] + bz;
    }
}

// ---------------------------------------------------------------------------------
// logits GEMM (dbuf + global_load_lds staging) + per-block top4/LSE partials
// ---------------------------------------------------------------------------------
__global__ __launch_bounds__(256) void logits_pre_kernel(
    const unsigned short* __restrict__ hnh, const unsigned short* __restrict__ hnl,
    const unsigned short* __restrict__ woh, const unsigned short* __restrict__ wol,
    const float* __restrict__ bo,
    float* __restrict__ pv, int* __restrict__ pc, float* __restrict__ pm, float* __restrict__ ps)
{
    __shared__ __align__(16) unsigned short sm[2*4*TS2];   // 32768 B; Cs aliases after loop
    const int bx = blockIdx.x, n0 = bx * 64;
    const int tid = threadIdx.x;
    const unsigned short* bth = woh + (size_t)bx * 16 * 2048;
    const unsigned short* btl = wol + (size_t)bx * 16 * 2048;
    const int row = tid >> 2, kq = (tid & 3) * 8;
    const int wave = tid >> 6, lane = tid & 63;
    const int fr = lane & 15, fq = lane >> 4;
    const unsigned short* a_h_src = hnh + (size_t)row*512 + kq;
    const unsigned short* a_l_src = hnl + (size_t)row*512 + kq;
    const unsigned short* b_h_src = bth + (size_t)tid*8;
    const unsigned short* b_l_src = btl + (size_t)tid*8;
    f32x4 acc[4];
    #pragma unroll
    for (int g = 0; g < 4; ++g) acc[g] = (f32x4){0.f,0.f,0.f,0.f};
    {
        unsigned short* nb = sm;
        gl2lds16(a_h_src, nb + 0*TS2 + tid*8);
        gl2lds16(a_l_src, nb + 1*TS2 + tid*8);
        gl2lds16(b_h_src, nb + 2*TS2 + tid*8);
        gl2lds16(b_l_src, nb + 3*TS2 + tid*8);
    }
    __syncthreads();
    for (int kt = 0; kt < 16; ++kt){
        if (kt < 15){
            unsigned short* nb = sm + (((kt+1)&1)*4)*TS2;
            gl2lds16(a_h_src + (kt+1)*32,   nb + 0*TS2 + tid*8);
            gl2lds16(a_l_src + (kt+1)*32,   nb + 1*TS2 + tid*8);
            gl2lds16(b_h_src + (kt+1)*2048, nb + 2*TS2 + tid*8);
            gl2lds16(b_l_src + (kt+1)*2048, nb + 3*TS2 + tid*8);
        }
        const unsigned short* cb = sm + ((kt&1)*4)*TS2;
        bf16x8 bh = *(const bf16x8*)(cb + 2*TS2 + (wave*16 + fr)*32 + fq*8);
        bf16x8 bl = *(const bf16x8*)(cb + 3*TS2 + (wave*16 + fr)*32 + fq*8);
        #pragma unroll
        for (int g = 0; g < 4; ++g){
            bf16x8 ah = *(const bf16x8*)(cb + 0*TS2 + (g*16 + fr)*32 + fq*8);
            bf16x8 al = *(const bf16x8*)(cb + 1*TS2 + (g*16 + fr)*32 + fq*8);
            acc[g] = __builtin_amdgcn_mfma_f32_16x16x32_bf16(ah, bh, acc[g], 0, 0, 0);
            acc[g] = __builtin_amdgcn_mfma_f32_16x16x32_bf16(ah, bl, acc[g], 0, 0, 0);
            acc[g] = __builtin_amdgcn_mfma_f32_16x16x32_bf16(al, bh, acc[g], 0, 0, 0);
        }
        __syncthreads();
    }
    // Cs (64x65 f32 = 16640 B) aliases sm; all LDS reads done (post-barrier).
    float (*Cs)[65] = (float(*)[65])sm;
    dump_C(acc, Cs, wave, lane);
    __syncthreads();
    const int c0 = (tid & 3) * 16;
    float bv[4] = {-INFINITY,-INFINITY,-INFINITY,-INFINITY};
    int bc[4] = {INT_MAX, INT_MAX, INT_MAX, INT_MAX};
    float m = -INFINITY, s = 0.f;
    #pragma unroll
    for (int j = 0; j < 16; ++j){
        float x = Cs[row][c0 + j] + bo[n0 + c0 + j];
        if (x > m){ s = s * expf(m - x) + 1.f; m = x; }
        else s += expf(x - m);
        ins4(bv, bc, x, n0 + c0 + j);
    }
    #pragma unroll
    for (int o = 1; o < 4; o <<= 1){
        float ov[4]; int oc[4];
        #pragma unroll
        for (int q = 0; q < 4; ++q){ ov[q] = __shfl_xor(bv[q], o); oc[q] = __shfl_xor(bc[q], o); }
        #pragma unroll
        for (int q = 0; q < 4; ++q) ins4(bv, bc, ov[q], oc[q]);
        float m2 = __shfl_xor(m, o), s2 = __shfl_xor(s, o);
        float M = fmaxf(m, m2);
        s = s * expf(m - M) + s2 * expf(m2 - M);
        m = M;
    }
    if ((tid & 3) == 0){
        const size_t base = (size_t)row * NE + (size_t)bx * 4;
        #pragma unroll
        for (int q = 0; q < 4; ++q){ pv[base + q] = bv[q]; pc[base + q] = bc[q]; }
        pm[row * NSP + bx] = m; ps[row * NSP + bx] = s;
    }
}

// final: dbuf 6-tile [A0h|A0l|A1h|A1l|Bh|Bl] staged via global_load_lds.
// grid = (m-quads, NSP): same-Wo-tile blocks adjacent in dispatch order.
__global__ __launch_bounds__(256) void final_pre_kernel(
    const unsigned short* __restrict__ hnh, const unsigned short* __restrict__ hnl,
    const int* __restrict__ rmap, const float* __restrict__ lse_all,
    const unsigned short* __restrict__ woh, const unsigned short* __restrict__ wol,
    const float* __restrict__ bo, float* __restrict__ out)
{
    __shared__ __align__(16) unsigned short sm[2*6*TS2];   // 49152 B
    __shared__ int sidx[64*FMBL]; __shared__ float subm[64*FMBL];
    const int tid = threadIdx.x;
    const int bx = blockIdx.y, n0 = bx * 64;
    const int mbase = blockIdx.x * (64 * FMBL);
    if (tid < 64*FMBL){ int g = rmap[mbase + tid]; sidx[tid] = g; subm[tid] = lse_all[g]; }
    __syncthreads();
    const int row = tid >> 2, kq = (tid & 3) * 8;
    const int wave = tid >> 6, lane = tid & 63;
    const int fr = lane & 15, fq = lane >> 4;
    const unsigned short* bth = woh + (size_t)bx * 16 * 2048;
    const unsigned short* btl = wol + (size_t)bx * 16 * 2048;
    const unsigned short* a0h_src = hnh + (size_t)sidx[row] * 512 + kq;
    const unsigned short* a0l_src = hnl + (size_t)sidx[row] * 512 + kq;
    const unsigned short* a1h_src = hnh + (size_t)sidx[64 + row] * 512 + kq;
    const unsigned short* a1l_src = hnl + (size_t)sidx[64 + row] * 512 + kq;
    const unsigned short* b_h_src = bth + (size_t)tid*8;
    const unsigned short* b_l_src = btl + (size_t)tid*8;
    f32x4 acc[FMBL][4];
    #pragma unroll
    for (int mb = 0; mb < FMBL; ++mb)
        #pragma unroll
        for (int g = 0; g < 4; ++g) acc[mb][g] = (f32x4){0.f,0.f,0.f,0.f};
    {
        unsigned short* nb = sm;
        gl2lds16(a0h_src, nb + 0*TS2 + tid*8);
        gl2lds16(a0l_src, nb + 1*TS2 + tid*8);
        gl2lds16(a1h_src, nb + 2*TS2 + tid*8);
        gl2lds16(a1l_src, nb + 3*TS2 + tid*8);
        gl2lds16(b_h_src, nb + 4*TS2 + tid*8);
        gl2lds16(b_l_src, nb + 5*TS2 + tid*8);
    }
    __syncthreads();
    for (int kt = 0; kt < 16; ++kt){
        if (kt < 15){
            unsigned short* nb = sm + (((kt+1)&1)*6)*TS2;
            gl2lds16(a0h_src + (kt+1)*32,   nb + 0*TS2 + tid*8);
            gl2lds16(a0l_src + (kt+1)*32,   nb + 1*TS2 + tid*8);
            gl2lds16(a1h_src + (kt+1)*32,   nb + 2*TS2 + tid*8);
            gl2lds16(a1l_src + (kt+1)*32,   nb + 3*TS2 + tid*8);
            gl2lds16(b_h_src + (kt+1)*2048, nb + 4*TS2 + tid*8);
            gl2lds16(b_l_src + (kt+1)*2048, nb + 5*TS2 + tid*8);
        }
        const unsigned short* cb = sm + ((kt&1)*6)*TS2;
        bf16x8 bh = *(const bf16x8*)(cb + 4*TS2 + (wave*16 + fr)*32 + fq*8);
        bf16x8 bl = *(const bf16x8*)(cb + 5*TS2 + (wave*16 + fr)*32 + fq*8);
        #pragma unroll
        for (int mb = 0; mb < FMBL; ++mb){
            #pragma unroll
            for (int g = 0; g < 4; ++g){
                bf16x8 ah = *(const bf16x8*)(cb + (2*mb+0)*TS2 + (g*16 + fr)*32 + fq*8);
                bf16x8 al = *(const bf16x8*)(cb + (2*mb+1)*TS2 + (g*16 + fr)*32 + fq*8);
                acc[mb][g] = __builtin_amdgcn_mfma_f32_16x16x32_bf16(ah, bh, acc[mb][g], 0, 0, 0);
                acc[mb][g] = __builtin_amdgcn_mfma_f32_16x16x32_bf16(ah, bl, acc[mb][g], 0, 0, 0);
                acc[mb][g] = __builtin_amdgcn_mfma_f32_16x16x32_bf16(al, bh, acc[mb][g], 0, 0, 0);
            }
        }
        __syncthreads();
    }
    // direct fragment->global epilogue
    const int col = n0 + wave*16 + fr;
    const float bz = bo[col];
    #pragma unroll
    for (int mb = 0; mb < FMBL; ++mb){
        #pragma unroll
        for (int g = 0; g < 4; ++g){
            const int rb = mb*64 + g*16 + fq*4;
            #pragma unroll
            for (int r = 0; r < 4; ++r){
                const int rowi = rb + r;
                out[(size_t)(mbase + rowi) * VOC + col] = acc[mb][g][r] + bz - subm[rowi];
            }
        }
    }
}

// =================================================================================
// ======================== fallback (R4, fp32-convert) path =======================
// =================================================================================
__device__ __forceinline__ void mfma_core(
    const float* __restrict__ Abase, const int* __restrict__ ridx, int mbase,
    const float* __restrict__ B, int ldb, int n0,
    unsigned short (&Ah)[64][40], unsigned short (&Al)[64][40],
    unsigned short (&Bh)[64][40], unsigned short (&Bl)[64][40],
    int (&sidx)[64], f32x4 (&acc)[4])
{
    const int tid = threadIdx.x;
    if (tid < 64) sidx[tid] = ridx ? ridx[mbase + tid] : (mbase + tid);
    #pragma unroll
    for (int g = 0; g < 4; ++g) acc[g] = (f32x4){0.f, 0.f, 0.f, 0.f};
    const int wave = tid >> 6, lane = tid & 63;
    const int am = tid >> 2, ak0 = (tid & 3) * 8;
    const int bn = tid & 63, br0 = (tid >> 6) * 8;
    __syncthreads();
    const float* bcol = B + n0 + bn;
    for (int kt = 0; kt < 16; ++kt){
        {
            const float* ap = Abase + (size_t)sidx[am] * HD + kt * 32 + ak0;
            float4 x0 = *(const float4*)ap, x1 = *(const float4*)(ap + 4);
            float xs[8] = {x0.x, x0.y, x0.z, x0.w, x1.x, x1.y, x1.z, x1.w};
            union { unsigned short u[8]; uint4 v; } h8, l8;
            #pragma unroll
            for (int j = 0; j < 8; ++j){
                unsigned short h = f2bf(xs[j]);
                h8.u[j] = h; l8.u[j] = f2bf(xs[j] - bf2f(h));
            }
            *(uint4*)&Ah[am][ak0] = h8.v;
            *(uint4*)&Al[am][ak0] = l8.v;
        }
        {
            const float* bp = bcol + (size_t)(kt * 32 + br0) * ldb;
            union { unsigned short u[8]; uint4 v; } h8, l8;
            #pragma unroll
            for (int j = 0; j < 8; ++j){
                float x = bp[(size_t)j * ldb];
                unsigned short h = f2bf(x);
                h8.u[j] = h; l8.u[j] = f2bf(x - bf2f(h));
            }
            *(uint4*)&Bh[bn][br0] = h8.v;
            *(uint4*)&Bl[bn][br0] = l8.v;
        }
        __syncthreads();
        bf16x8 bh = *(const bf16x8*)&Bh[wave * 16 + (lane & 15)][(lane >> 4) * 8];
        bf16x8 bl = *(const bf16x8*)&Bl[wave * 16 + (lane & 15)][(lane >> 4) * 8];
        #pragma unroll
        for (int g = 0; g < 4; ++g){
            bf16x8 ah = *(const bf16x8*)&Ah[g * 16 + (lane & 15)][(lane >> 4) * 8];
            bf16x8 al = *(const bf16x8*)&Al[g * 16 + (lane & 15)][(lane >> 4) * 8];
            acc[g] = __builtin_amdgcn_mfma_f32_16x16x32_bf16(ah, bh, acc[g], 0, 0, 0);
            acc[g] = __builtin_amdgcn_mfma_f32_16x16x32_bf16(ah, bl, acc[g], 0, 0, 0);
            acc[g] = __builtin_amdgcn_mfma_f32_16x16x32_bf16(al, bh, acc[g], 0, 0, 0);
        }
        __syncthreads();
    }
}

__global__ __launch_bounds__(256) void gates_mfma_kernel(
    const float* __restrict__ E, const int* __restrict__ inp, const float* __restrict__ h_cur,
    const float* __restrict__ W_ih, const float* __restrict__ W_hh,
    const float* __restrict__ b_ih, const float* __restrict__ b_hh,
    float* __restrict__ gbuf)
{
    __shared__ unsigned short Ah[64][40], Al[64][40], Bh[64][40], Bl[64][40];
    __shared__ int sidx[64];
    __shared__ float Cs[64][65];
    const int z = blockIdx.y;
    const int n0 = blockIdx.x * 64;
    const int tid = threadIdx.x;
    f32x4 acc[4];
    mfma_core(z ? h_cur : E, z ? nullptr : inp, 0,
              z ? W_hh : W_ih, G3, n0, Ah, Al, Bh, Bl, sidx, acc);
    dump_C(acc, Cs, tid >> 6, tid & 63);
    __syncthreads();
    const float* bias = z ? b_hh : b_ih;
    const int row = tid >> 2, c0 = (tid & 3) * 16;
    float* gp = gbuf + (size_t)z * BKR * G3 + (size_t)row * G3 + n0 + c0;
    #pragma unroll
    for (int q = 0; q < 4; ++q){
        float4 bz = *(const float4*)(bias + n0 + c0 + q * 4);
        float4 v;
        v.x = Cs[row][c0 + q*4 + 0] + bz.x;
        v.y = Cs[row][c0 + q*4 + 1] + bz.y;
        v.z = Cs[row][c0 + q*4 + 2] + bz.z;
        v.w = Cs[row][c0 + q*4 + 3] + bz.w;
        *(float4*)(gp + q * 4) = v;
    }
}

__global__ __launch_bounds__(256) void logits_topk_kernel(const float* __restrict__ h_new,
    const float* __restrict__ Wo, const float* __restrict__ bo,
    float* __restrict__ pv, int* __restrict__ pc, float* __restrict__ pm, float* __restrict__ ps)
{
    __shared__ unsigned short Ah[64][40], Al[64][40], Bh[64][40], Bl[64][40];
    __shared__ int sidx[64];
    __shared__ float Cs[64][65];
    const int bx = blockIdx.x, n0 = bx * 64;
    const int tid = threadIdx.x;
    f32x4 acc[4];
    mfma_core(h_new, nullptr, 0, Wo, VOC, n0, Ah, Al, Bh, Bl, sidx, acc);
    dump_C(acc, Cs, tid >> 6, tid & 63);
    __syncthreads();
    const int row = tid >> 2, c0 = (tid & 3) * 16;
    float bv[4] = {-INFINITY,-INFINITY,-INFINITY,-INFINITY};
    int bc[4] = {INT_MAX, INT_MAX, INT_MAX, INT_MAX};
    float m = -INFINITY, s = 0.f;
    #pragma unroll
    for (int j = 0; j < 16; ++j){
        float x = Cs[row][c0 + j] + bo[n0 + c0 + j];
        if (x > m){ s = s * expf(m - x) + 1.f; m = x; }
        else s += expf(x - m);
        ins4(bv, bc, x, n0 + c0 + j);
    }
    #pragma unroll
    for (int o = 1; o < 4; o <<= 1){
        float ov[4]; int oc[4];
        #pragma unroll
        for (int q = 0; q < 4; ++q){ ov[q] = __shfl_xor(bv[q], o); oc[q] = __shfl_xor(bc[q], o); }
        #pragma unroll
        for (int q = 0; q < 4; ++q) ins4(bv, bc, ov[q], oc[q]);
        float m2 = __shfl_xor(m, o), s2 = __shfl_xor(s, o);
        float M = fmaxf(m, m2);
        s = s * expf(m - M) + s2 * expf(m2 - M);
        m = M;
    }
    if ((tid & 3) == 0){
        const size_t base = (size_t)row * NE + (size_t)bx * 4;
        #pragma unroll
        for (int q = 0; q < 4; ++q){ pv[base + q] = bv[q]; pc[base + q] = bc[q]; }
        pm[row * NSP + bx] = m; ps[row * NSP + bx] = s;
    }
}

__global__ __launch_bounds__(256) void final_mfma_kernel(const float* __restrict__ h_new_all,
    const int* __restrict__ rmap, const float* __restrict__ lse_all,
    const float* __restrict__ Wo, const float* __restrict__ bo, float* __restrict__ out)
{
    __shared__ unsigned short Ah[64][40], Al[64][40], Bh[64][40], Bl[64][40];
    __shared__ int sidx[64];
    __shared__ float Cs[64][65];
    __shared__ float subm[64];
    const int n0 = blockIdx.x * 64, mb = blockIdx.y * 64;
    const int tid = threadIdx.x;
    f32x4 acc[4];
    mfma_core(h_new_all, rmap, mb, Wo, VOC, n0, Ah, Al, Bh, Bl, sidx, acc);
    dump_C(acc, Cs, tid >> 6, tid & 63);
    if (tid < 64) subm[tid] = lse_all[sidx[tid]];
    __syncthreads();
    const int row = tid >> 2, c0 = (tid & 3) * 16;
    const float sub = subm[row];
    float* op = out + (size_t)(mb + row) * VOC + n0 + c0;
    #pragma unroll
    for (int q = 0; q < 4; ++q){
        float4 bz = *(const float4*)(bo + n0 + c0 + q * 4);
        float4 v;
        v.x = Cs[row][c0 + q*4 + 0] + bz.x - sub;
        v.y = Cs[row][c0 + q*4 + 1] + bz.y - sub;
        v.z = Cs[row][c0 + q*4 + 2] + bz.z - sub;
        v.w = Cs[row][c0 + q*4 + 3] + bz.w - sub;
        *(float4*)(op + q * 4) = v;
    }
}

// =================================================================================
// ============================ shared non-GEMM kernels ============================
// =================================================================================

__global__ void gru_combine_kernel(const float* __restrict__ gbuf, const float* __restrict__ h_cur,
    float* __restrict__ h_new, unsigned short* __restrict__ hnh, unsigned short* __restrict__ hnl)
{
    int x = blockIdx.x * 256 + threadIdx.x;
    int i = x >> 9, j = x & 511;
    const float* gi = gbuf + (size_t)i * G3;
    const float* gh = gbuf + (size_t)BKR * G3 + (size_t)i * G3;
    float ir = gi[j], iz = gi[j + 512], inn = gi[j + 1024];
    float hr = gh[j], hz = gh[j + 512], hnv = gh[j + 1024];
    float r  = 1.f / (1.f + expf(-(ir + hr)));
    float zz = 1.f / (1.f + expf(-(iz + hz)));
    float n  = tanhf(inn + r * hnv);
    float v = (1.f - zz) * n + zz * h_cur[x];
    h_new[x] = v;
    if (hnh){
        unsigned short h = f2bf(v);
        hnh[x] = h; hnl[x] = f2bf(v - bf2f(h));
    }
}

__global__ __launch_bounds__(256) void topk_phase_b(
    const float* __restrict__ pv, const int* __restrict__ pc,
    const float* __restrict__ pm, const float* __restrict__ ps,
    int t,
    float* __restrict__ scores_all, int* __restrict__ preds_all, int* __restrict__ syms_all,
    float* __restrict__ ss, int* __restrict__ inp, float* __restrict__ lse_all,
    const float* __restrict__ h_new, float* __restrict__ h_cur,
    const float* __restrict__ E,
    unsigned short* __restrict__ hch, unsigned short* __restrict__ hcl,
    unsigned short* __restrict__ eih, unsigned short* __restrict__ eil)
{
    const int b = blockIdx.x, tid = threadIdx.x;
    const int wave = tid >> 6, lane = tid & 63;
    const int row = b * KBEAM + wave;

    float bv[4] = {-INFINITY,-INFINITY,-INFINITY,-INFINITY};
    int bc[4] = {INT_MAX, INT_MAX, INT_MAX, INT_MAX};
    for (int e = lane; e < NE; e += 64)
        ins4(bv, bc, pv[(size_t)row * NE + e], pc[(size_t)row * NE + e]);
    #pragma unroll
    for (int o = 1; o < 64; o <<= 1){
        float ov[4]; int oc[4];
        #pragma unroll
        for (int q = 0; q < 4; ++q){ ov[q] = __shfl_xor(bv[q], o); oc[q] = __shfl_xor(bc[q], o); }
        #pragma unroll
        for (int q = 0; q < 4; ++q) ins4(bv, bc, ov[q], oc[q]);
    }
    float m = -INFINITY, s = 0.f;
    for (int e = lane; e < NSP; e += 64){
        float m2 = pm[row * NSP + e], s2 = ps[row * NSP + e];
        float M = fmaxf(m, m2);
        s = s * expf(m - M) + s2 * expf(m2 - M);
        m = M;
    }
    #pragma unroll
    for (int o = 1; o < 64; o <<= 1){
        float m2 = __shfl_xor(m, o), s2 = __shfl_xor(s, o);
        float M = fmaxf(m, m2);
        s = s * expf(m - M) + s2 * expf(m2 - M);
        m = M;
    }
    __shared__ float rtv[KBEAM][4]; __shared__ int rtc[KBEAM][4];
    __shared__ float rlse[KBEAM];
    if (lane == 0){
        #pragma unroll
        for (int q = 0; q < 4; ++q){ rtv[wave][q] = bv[q]; rtc[wave][q] = bc[q]; }
        rlse[wave] = m + logf(s);
    }
    __syncthreads();
    __shared__ int spred[KBEAM]; __shared__ int ssym[KBEAM];
    if (tid == 0){
        float gv[4] = {-INFINITY,-INFINITY,-INFINITY,-INFINITY};
        int gc[4] = {INT_MAX, INT_MAX, INT_MAX, INT_MAX};
        #pragma unroll
        for (int kl = 0; kl < KBEAM; ++kl){
            const int r2 = b * KBEAM + kl;
            float lse = rlse[kl];
            lse_all[t * BKR + r2] = lse;
            float off = ss[r2] - lse;
            if (off == -INFINITY){
                #pragma unroll
                for (int q = 0; q < 4; ++q) ins4(gv, gc, -INFINITY, kl * VOC + q);
            } else {
                #pragma unroll
                for (int q = 0; q < 4; ++q) ins4(gv, gc, rtv[kl][q] + off, kl * VOC + rtc[kl][q]);
            }
        }
        #pragma unroll
        for (int u = 0; u < KBEAM; ++u){
            int cand = gc[u]; float val = gv[u];
            int sym = cand % VOC; int pg = b * KBEAM + cand / VOC;
            int slot = b * KBEAM + u;
            scores_all[t * BKR + slot] = val;
            syms_all[t * BKR + slot] = sym;
            preds_all[t * BKR + slot] = pg;
            ss[slot] = (sym == EOS_TOK) ? -INFINITY : val;
            inp[slot] = sym;
            spred[u] = pg; ssym[u] = sym;
        }
    }
    __syncthreads();
    for (int x = tid; x < KBEAM * HD; x += 256){
        int u = x >> 9, j = x & 511;
        const int idx = (b * KBEAM + u) * HD + j;
        float v = h_new[spred[u] * HD + j];
        h_cur[idx] = v;
        if (hch){
            unsigned short h = f2bf(v);
            hch[idx] = h; hcl[idx] = f2bf(v - bf2f(h));
            float e = E[(size_t)ssym[u] * HD + j];
            unsigned short eh = f2bf(e);
            eih[idx] = eh; eil[idx] = f2bf(e - bf2f(eh));
        }
    }
}

__global__ void init_kernel(const float* __restrict__ enc_h, const float* __restrict__ E,
    float* __restrict__ h_cur, float* __restrict__ ss, int* __restrict__ inp,
    unsigned short* __restrict__ hch, unsigned short* __restrict__ hcl,
    unsigned short* __restrict__ eih, unsigned short* __restrict__ eil)
{
    const int i = blockIdx.x;
    for (int j = threadIdx.x; j < HD; j += blockDim.x){
        float v = enc_h[(i & (BATCH - 1)) * HD + j];
        h_cur[i * HD + j] = v;
        if (hch){
            const int idx = i * HD + j;
            unsigned short h = f2bf(v);
            hch[idx] = h; hcl[idx] = f2bf(v - bf2f(h));
            float e = E[(size_t)SOS_TOK * HD + j];
            unsigned short eh = f2bf(e);
            eih[idx] = eh; eil[idx] = f2bf(e - bf2f(eh));
        }
    }
    if (i == 0 && threadIdx.x < BKR){
        ss[threadIdx.x] = ((threadIdx.x & (KBEAM - 1)) == 0) ? 0.f : -INFINITY;
        inp[threadIdx.x] = SOS_TOK;
    }
}

// ================= backtrack (single block, LDS-staged, parallel) =================
__global__ __launch_bounds__(256) void backtrack_kernel(
    const float* __restrict__ scores_all, const int* __restrict__ preds_all, const int* __restrict__ syms_all,
    const float* __restrict__ h_new_all, float* __restrict__ hn_fin,
    int* __restrict__ rmap, float* __restrict__ out)
{
    __shared__ int   l_syms[T_STEPS*BKR];
    __shared__ int   l_preds[T_STEPS*BKR];
    __shared__ float l_scores[T_STEPS*BKR];
    __shared__ int   outrow_s[T_STEPS*BKR];
    __shared__ int   cursym_s[T_STEPS*BKR];
    __shared__ int tpred[64]; __shared__ float sfin[64]; __shared__ int lensq[64];
    __shared__ int eosf[BATCH];
    __shared__ int orow[64], csym[64], npred_s[64];
    __shared__ int cp_slot[64], cp_src[64]; __shared__ int nc_b[BATCH];
    __shared__ int reidx[64];
    const int tid = threadIdx.x;

    for (int x = tid; x < T_STEPS*BKR; x += 256){
        l_syms[x]   = syms_all[x];
        l_preds[x]  = preds_all[x];
        l_scores[x] = scores_all[x];
    }
    for (int x = tid; x < BKR*HD; x += 256) hn_fin[x] = 0.f;
    __syncthreads();

    if (tid < BATCH){
        const int b = tid;
        float v[KBEAM]; int used[KBEAM];
        #pragma unroll
        for (int k = 0; k < KBEAM; ++k){ v[k] = l_scores[(T_STEPS-1)*BKR + b*KBEAM + k]; used[k] = 0; }
        #pragma unroll
        for (int u = 0; u < KBEAM; ++u){
            int best = -1; float bvv = 0.f;
            #pragma unroll
            for (int k = 0; k < KBEAM; ++k) if (!used[k] && (best < 0 || v[k] > bvv)){ best = k; bvv = v[k]; }
            used[best] = 1;
            tpred[b*KBEAM+u] = b*KBEAM + best;
            sfin[b*KBEAM+u] = bvv;
            lensq[b*KBEAM+u] = T_STEPS;
        }
        eosf[b] = 0;
    }
    __syncthreads();

    for (int t = T_STEPS-1; t >= 0; --t){
        if (tid < 64){
            int tp = tpred[tid];
            orow[tid]    = tp;
            csym[tid]    = l_syms[t*BKR + tp];
            npred_s[tid] = l_preds[t*BKR + tp];
        }
        __syncthreads();
        if (tid < BATCH){
            const int b = tid;
            int eos[KBEAM]; int cnt = 0;
            #pragma unroll
            for (int k = 0; k < KBEAM; ++k) eos[k] = (l_syms[t*BKR + b*KBEAM + k] == EOS_TOK);
            int nc = 0;
            #pragma unroll
            for (int k = 0; k < KBEAM; ++k) if (eos[k]){
                int higher = 0;
                #pragma unroll
                for (int k2 = k+1; k2 < KBEAM; ++k2) higher += eos[k2];
                int occ = eosf[b] + higher;
                int rk = KBEAM - (occ % KBEAM) - 1;
                int slot = b*KBEAM + rk;
                int j = b*KBEAM + k;
                npred_s[slot] = l_preds[t*BKR + j];
                orow[slot]    = j;
                csym[slot]    = l_syms[t*BKR + j];
                sfin[slot]    = l_scores[t*BKR + j];
                lensq[slot]   = t + 1;
                cp_slot[b*KBEAM + nc] = slot;
                cp_src[b*KBEAM + nc]  = l_preds[t*BKR + j];
                ++nc; ++cnt;
            }
            nc_b[b] = nc;
            eosf[b] += cnt;
        }
        __syncthreads();
        if (tid < 64){
            outrow_s[t*BKR + tid] = orow[tid];
            cursym_s[t*BKR + tid] = csym[tid];
            tpred[tid] = npred_s[tid];
        }
        {
            const int e = tid >> 2;
            const int eb = e >> 2, eq = e & 3;
            if (eq < nc_b[eb]){
                const int slot = cp_slot[eb*KBEAM + eq];
                const int src  = cp_src[eb*KBEAM + eq];
                const float4* sp = (const float4*)(h_new_all + (size_t)(t*BKR + src)*HD);
                float4* dp = (float4*)(hn_fin + (size_t)slot*HD);
                for (int j = (tid & 3); j < HD/4; j += 4) dp[j] = sp[j];
            }
        }
        __syncthreads();
    }

    if (tid < BATCH){
        const int b = tid;
        float v[KBEAM]; int used[KBEAM];
        #pragma unroll
        for (int k = 0; k < KBEAM; ++k){ v[k] = sfin[b*KBEAM+k]; used[k] = 0; }
        #pragma unroll
        for (int u = 0; u < KBEAM; ++u){
            int best = -1; float bvv = 0.f;
            #pragma unroll
            for (int k = 0; k < KBEAM; ++k) if (!used[k] && (best < 0 || v[k] > bvv)){ best = k; bvv = v[k]; }
            used[best] = 1;
            reidx[b*KBEAM+u] = best;
            out[O_SSRT + b*KBEAM + u] = bvv;
            out[O_LENS + b*KBEAM + u] = (float)lensq[b*KBEAM + best];
        }
    }
    __syncthreads();
    for (int x = tid; x < T_STEPS*BATCH; x += 256){
        int t2 = x >> 4, b = x & 15;
        rmap[x] = t2*BKR + outrow_s[t2*BKR + b*KBEAM + reidx[b*KBEAM]];
    }
    for (int x = tid; x < T_STEPS*BKR; x += 256){
        int t2 = x >> 6, rem = x & 63, b = rem >> 2, k = rem & 3;
        out[O_SEQS + x] = (float)cursym_s[t2*BKR + b*KBEAM + reidx[b*KBEAM + k]];
    }
    for (int x = tid; x < BATCH*HD; x += 256){
        int b = x >> 9, j = x & 511;
        out[O_HID + x] = hn_fin[(b*KBEAM + reidx[b*KBEAM])*HD + j];
    }
}

extern "C" void kernel_launch(void* const* d_in, const int* in_sizes, int n_in,
                              void* d_out, int out_size, void* d_ws, size_t ws_size,
                              hipStream_t stream)
{
    const float* enc_h = (const float*)d_in[0];
    const float* E     = (const float*)d_in[1];
    const float* W_ih  = (const float*)d_in[2];
    const float* W_hh  = (const float*)d_in[3];
    const float* b_ih  = (const float*)d_in[4];
    const float* b_hh  = (const float*)d_in[5];
    const float* Wo    = (const float*)d_in[6];
    const float* bo    = (const float*)d_in[7];
    float* out = (float*)d_out;

    float* w = (float*)d_ws;
    float* h_cur      = w + OFF_HCUR;
    float* gbuf       = w + OFF_GBUF;
    float* h_new_all  = w + OFF_HNEW;
    float* lse_all    = w + OFF_LSE;
    float* ss         = w + OFF_SS;
    float* scores_all = w + OFF_SCORES;
    float* hn_fin     = w + OFF_HNFIN;
    float* pv         = w + OFF_PV;
    float* pm         = w + OFF_PM;
    float* ps         = w + OFF_PS;
    int* wi         = (int*)(w + OFF_FEND);
    int* inp        = wi + IOFF_INP;
    int* preds_all  = wi + IOFF_PREDS;
    int* syms_all   = wi + IOFF_SYMS;
    int* rmap       = wi + IOFF_RMAP;
    int* pc         = wi + IOFF_PC;
    unsigned short* sb = (unsigned short*)(wi + IOFF_END);
    unsigned short* woh = sb + S_WOH;
    unsigned short* wol = sb + S_WOL;
    unsigned short* wgh = sb + S_WGH;
    unsigned short* wgl = sb + S_WGL;
    unsigned short* hnh = sb + S_HNH;
    unsigned short* hnl = sb + S_HNL;
    unsigned short* hch = sb + S_HCH;
    unsigned short* hcl = sb + S_HCL;
    unsigned short* eih = sb + S_EIH;
    unsigned short* eil = sb + S_EIL;

    const size_t NEED = (size_t)OFF_FEND*4 + (size_t)IOFF_END*4 + (size_t)S_END*2;
    const bool pre = (ws_size >= NEED);

    init_kernel<<<dim3(BKR), 256, 0, stream>>>(enc_h, E, h_cur, ss, inp,
        pre ? hch : nullptr, hcl, eih, eil);
    if (pre){
        prepack_kernel<<<dim3(NSP, 16), 256, 0, stream>>>(Wo, VOC, woh, wol);
        prepack_kernel<<<dim3(NBG, 16), 256, 0, stream>>>(W_ih, G3, wgh, wgl);
        prepack_kernel<<<dim3(NBG, 16), 256, 0, stream>>>(W_hh, G3,
            wgh + (size_t)NBG*16*2048, wgl + (size_t)NBG*16*2048);
    }
    for (int t = 0; t < T_STEPS; ++t){
        float* h_new_t = h_new_all + (size_t)t * BKR * HD;
        unsigned short* hnh_t = hnh + (size_t)t * BKR * HD;
        unsigned short* hnl_t = hnl + (size_t)t * BKR * HD;
        if (pre){
            gates_pre_kernel<<<dim3(NBG, 2), 256, 0, stream>>>(eih, eil, hch, hcl,
                wgh, wgl, b_ih, b_hh, gbuf);
            gru_combine_kernel<<<dim3(BKR*HD/256), 256, 0, stream>>>(gbuf, h_cur, h_new_t,
                hnh_t, hnl_t);
            logits_pre_kernel<<<dim3(NSP), 256, 0, stream>>>(hnh_t, hnl_t, woh, wol, bo,
                pv, pc, pm, ps);
            topk_phase_b<<<dim3(BATCH), 256, 0, stream>>>(pv, pc, pm, ps, t, scores_all, preds_all, syms_all,
                ss, inp, lse_all, h_new_t, h_cur, E,
                hch, hcl, eih, eil);
        } else {
            gates_mfma_kernel<<<dim3(NBG, 2), 256, 0, stream>>>(E, inp, h_cur, W_ih, W_hh, b_ih, b_hh, gbuf);
            gru_combine_kernel<<<dim3(BKR*HD/256), 256, 0, stream>>>(gbuf, h_cur, h_new_t,
                nullptr, hnl_t);
            logits_topk_kernel<<<dim3(NSP), 256, 0, stream>>>(h_new_t, Wo, bo, pv, pc, pm, ps);
            topk_phase_b<<<dim3(BATCH), 256, 0, stream>>>(pv, pc, pm, ps, t, scores_all, preds_all, syms_all,
                ss, inp, lse_all, h_new_t, h_cur, E,
                nullptr, hcl, eih, eil);
        }
    }
    backtrack_kernel<<<dim3(1), 256, 0, stream>>>(scores_all, preds_all, syms_all, h_new_all, hn_fin,
                                                  rmap, out);
    if (pre){
        final_pre_kernel<<<dim3((T_STEPS*BATCH)/(64*FMBL), NSP), 256, 0, stream>>>(
            hnh, hnl, rmap, lse_all, woh, wol, bo, out);
    } else {
        final_mfma_kernel<<<dim3(NSP, T_STEPS*BATCH/64), 256, 0, stream>>>(h_new_all, rmap, lse_all, Wo, bo, out);
    }
}